// Round 9
// baseline (204.531 us; speedup 1.0000x reference)
//
#include <hip/hip_runtime.h>
#include <hip/hip_bf16.h>

typedef __attribute__((ext_vector_type(8))) short short8;
typedef __attribute__((ext_vector_type(4))) float floatx4;

#define NNODES 40000
#define NPW 4                    // nodes per wave
#define WAVES 8                  // waves per block (512 threads)
#define NPB (NPW * WAVES)        // 32 nodes per block
#define NBLK (NNODES / NPB)      // 1250 blocks, exact

#define U2E_ELEMS (100000 * 64)
#define WS_ALIGN 256
#define WS_NEEDED ((size_t)U2E_ELEMS * 2 + WS_ALIGN)

// Dtype world (MEASURED, rounds 2-8): float tensors fp32 in memory, indices
// int32, output fp32. Fixed ~86-90us harness overhead sits outside the kernels;
// only kernel time is controllable. bf16 pre-converted u2e = 94us kernel (r7)
// vs direct fp32 = 116us (r8) -> keep the convert dispatch, drop the sniff.

__device__ __forceinline__ float bf2f(unsigned short s) {
    return __uint_as_float(((unsigned int)s) << 16);
}
__device__ __forceinline__ unsigned short f2bf(float f) {
    unsigned int u = __float_as_uint(f);
    u += 0x7fffu + ((u >> 16) & 1u);   // RNE
    return (unsigned short)(u >> 16);
}
__device__ __forceinline__ unsigned short f2bf_fast(float f) {
#if __has_builtin(__builtin_amdgcn_cvt_pk_bf16_f32)
    auto r = __builtin_amdgcn_cvt_pk_bf16_f32(f, f);   // 1 inst, RNE
    unsigned int u; __builtin_memcpy(&u, &r, 4);
    return (unsigned short)u;
#else
    return f2bf(f);
#endif
}
// 8 consecutive fp32 -> bf16x8 fragment
__device__ __forceinline__ short8 cvt8(const float* fp) {
    floatx4 a = *(const floatx4*)fp;
    floatx4 b = *(const floatx4*)(fp + 4);
    short8 r;
    #pragma unroll
    for (int j = 0; j < 4; ++j) {
        r[j]     = (short)f2bf_fast(a[j]);
        r[4 + j] = (short)f2bf_fast(b[j]);
    }
    return r;
}

// One-shot u2e fp32->bf16 into workspace (25.6MB rd / 12.8MB wr ~ 7us)
__global__ __launch_bounds__(256) void convert_u2e(
    const float* __restrict__ u2e, unsigned short* __restrict__ ub) {
    const size_t i = ((size_t)blockIdx.x * 256 + threadIdx.x) * 8;
    if (i < U2E_ELEMS) *(short8*)(ub + i) = cvt8(u2e + i);
}

// One wave = one node (32 edges = 2 MFMA M-tiles). MFMA layouts (m89/m97-verified):
// A-frag: lane holds A[m=lane&15][k=(lane>>4)*8+j]; B-frag: B[k=(lane>>4)*8+j][n=lane&15];
// C/D: col=lane&15, row=(lane>>4)*4+reg.
// Bias fold: C-init = b[col] broadcast (b1v[nt]/b2v[nt]) -> no epilogue adds.
// PRE=1: u2e gathered from pre-converted bf16 table; PRE=0: direct fp32+cvt.
template<int PRE>
__global__ __launch_bounds__(512, 4) void gat_fused(
    const int*   __restrict__ nodes,
    const int*   __restrict__ neigh,
    const float* __restrict__ u2f,           // [100000][64] fp32 (original)
    const unsigned short* __restrict__ u2b,  // [100000][64] bf16 (ws, PRE=1)
    const float* __restrict__ g2e,           // [50000][64]  fp32
    const float* __restrict__ w1,            // [64][128]
    const float* __restrict__ b1,            // [64]
    const float* __restrict__ w2,            // [64][64]
    const float* __restrict__ b2,            // [64]
    const float* __restrict__ w3,            // [64]
    float* __restrict__ out)                 // [40000][64] fp32
{
    __shared__ alignas(16) short w1f[16 * 64 * 8];      // 16 KB: W1 B-frags (nt,kc)
    __shared__ alignas(16) short w2f[8 * 64 * 8];       // 8 KB:  W2 B-frags
    __shared__ alignas(16) short hbuf[WAVES][32 * 72];  // 36 KB: H1 C->A relayout

    const int tid  = threadIdx.x;
    const int wv   = tid >> 6;
    const int lane = tid & 63;
    const int q    = lane >> 4;
    const int n16  = lane & 15;

    // ---- stage W fragments into LDS (once per block) ----
    for (int i = tid; i < 16 * 64; i += 512) {
        int s = i >> 6, slot = i & 63;
        int nt = s >> 2, kc = s & 3;
        int row = nt * 16 + (slot & 15);
        int k   = kc * 32 + (slot >> 4) * 8;
        *(short8*)&w1f[i * 8] = cvt8(w1 + (size_t)row * 128 + k);
    }
    for (int i = tid; i < 8 * 64; i += 512) {
        int s = i >> 6, slot = i & 63;
        int nt = s >> 1, kc = s & 1;
        int row = nt * 16 + (slot & 15);
        int k   = kc * 32 + (slot >> 4) * 8;
        *(short8*)&w2f[i * 8] = cvt8(w2 + (size_t)row * 64 + k);
    }
    float b1v[4], b2v[4], w3v[4];
    #pragma unroll
    for (int nt = 0; nt < 4; ++nt) {
        b1v[nt] = b1[nt * 16 + n16];
        b2v[nt] = b2[nt * 16 + n16];
        w3v[nt] = w3[nt * 16 + n16];
    }
    __syncthreads();   // weights read-only afterwards; hbuf per-wave exclusive

    const int n0 = blockIdx.x * NPB + wv * NPW;

    // ---- software pipeline state ----
    int gc, vc, c0, c1;    // idx stage feeding current frags
    int gn, vn, d0, d1;    // idx stage one node ahead
    short8 A00, A01, A10, A11, G0, G1;

    auto loadA = [&](int idx, int half) -> short8 {
        if (PRE) return *(const short8*)(u2b + (size_t)idx * 64 + half * 32 + q * 8);
        else     return cvt8(u2f + (size_t)idx * 64 + half * 32 + q * 8);
    };

    {   // prologue: idx(n0) -> frags(n0), idx(n0+1)
        gc = nodes[n0];
        size_t eb = (size_t)n0 * 32;
        vc = neigh[eb + (lane & 31)];
        c0 = neigh[eb + n16];
        c1 = neigh[eb + 16 + n16];
        A00 = loadA(c0, 0); A01 = loadA(c0, 1);
        A10 = loadA(c1, 0); A11 = loadA(c1, 1);
        G0  = cvt8(g2e + (size_t)gc * 64 + q * 8);
        G1  = cvt8(g2e + (size_t)gc * 64 + 32 + q * 8);
        int n1 = n0 + 1;
        gn = nodes[n1];
        size_t eb1 = (size_t)n1 * 32;
        vn = neigh[eb1 + (lane & 31)];
        d0 = neigh[eb1 + n16];
        d1 = neigh[eb1 + 16 + n16];
    }

    for (int it = 0; it < NPW; ++it) {
        const int n = n0 + it;
        const short8 a00 = A00, a01 = A01, a10 = A10, a11 = A11, g0 = G0, g1 = G1;
        const int idxv = vc;

        // ---- layer 1: H1[32x64] = [eu | g] @ W1^T ; acc init = b1 (bias fold) ----
        floatx4 acc[2][4];
        #pragma unroll
        for (int mt = 0; mt < 2; ++mt)
            #pragma unroll
            for (int nt = 0; nt < 4; ++nt) {
                floatx4 b4 = {b1v[nt], b1v[nt], b1v[nt], b1v[nt]};
                acc[mt][nt] = b4;
            }
        #pragma unroll
        for (int kc = 0; kc < 4; ++kc) {
            short8 x0 = (kc == 0) ? a00 : (kc == 1) ? a01 : (kc == 2) ? g0 : g1;
            short8 x1 = (kc == 0) ? a10 : (kc == 1) ? a11 : (kc == 2) ? g0 : g1;
            #pragma unroll
            for (int nt = 0; nt < 4; ++nt) {
                short8 b = *(const short8*)&w1f[((nt * 4 + kc) * 64 + lane) * 8];
                acc[0][nt] = __builtin_amdgcn_mfma_f32_16x16x32_bf16(x0, b, acc[0][nt], 0, 0, 0);
                acc[1][nt] = __builtin_amdgcn_mfma_f32_16x16x32_bf16(x1, b, acc[1][nt], 0, 0, 0);
            }
        }

        // ---- prefetch node it+1 frags, node it+2 indices ----
        if (it < NPW - 1) {
            A00 = loadA(d0, 0); A01 = loadA(d0, 1);
            A10 = loadA(d1, 0); A11 = loadA(d1, 1);
            G0  = cvt8(g2e + (size_t)gn * 64 + q * 8);
            G1  = cvt8(g2e + (size_t)gn * 64 + 32 + q * 8);
            gc = gn; vc = vn; c0 = d0; c1 = d1;
            int nn = n0 + it + 2; if (nn > NNODES - 1) nn = NNODES - 1;
            gn = nodes[nn];
            size_t eb2 = (size_t)nn * 32;
            vn = neigh[eb2 + (lane & 31)];
            d0 = neigh[eb2 + n16];
            d1 = neigh[eb2 + 16 + n16];
        }

        // ---- epilogue 1: relu + bf16 pack, C-layout -> row-major LDS ----
        __builtin_amdgcn_wave_barrier();   // prior a2 reads precede overwrite
        #pragma unroll
        for (int mt = 0; mt < 2; ++mt)
            #pragma unroll
            for (int nt = 0; nt < 4; ++nt)
                #pragma unroll
                for (int r = 0; r < 4; ++r) {
                    float v = fmaxf(acc[mt][nt][r], 0.f);
                    hbuf[wv][(mt * 16 + q * 4 + r) * 72 + nt * 16 + n16] = (short)f2bf_fast(v);
                }
        __builtin_amdgcn_wave_barrier();

        // ---- layer 2 A-frags from LDS (intra-wave, in-order) ----
        short8 a2[2][2];
        #pragma unroll
        for (int mt = 0; mt < 2; ++mt)
            #pragma unroll
            for (int kc = 0; kc < 2; ++kc)
                a2[mt][kc] = *(const short8*)&hbuf[wv][(mt * 16 + n16) * 72 + kc * 32 + q * 8];

        // ---- layer 2 MFMA; acc2 init = b2 (bias fold) ----
        floatx4 acc2[2][4];
        #pragma unroll
        for (int mt = 0; mt < 2; ++mt)
            #pragma unroll
            for (int nt = 0; nt < 4; ++nt) {
                floatx4 b4 = {b2v[nt], b2v[nt], b2v[nt], b2v[nt]};
                acc2[mt][nt] = b4;
            }
        #pragma unroll
        for (int kc = 0; kc < 2; ++kc)
            #pragma unroll
            for (int nt = 0; nt < 4; ++nt) {
                short8 b = *(const short8*)&w2f[((nt * 2 + kc) * 64 + lane) * 8];
                acc2[0][nt] = __builtin_amdgcn_mfma_f32_16x16x32_bf16(a2[0][kc], b, acc2[0][nt], 0, 0, 0);
                acc2[1][nt] = __builtin_amdgcn_mfma_f32_16x16x32_bf16(a2[1][kc], b, acc2[1][nt], 0, 0, 0);
            }

        // ---- logits in registers: tt[mt][r] = sum_nt relu(acc2)*w3 ----
        float tt[2][4];
        #pragma unroll
        for (int mt = 0; mt < 2; ++mt)
            #pragma unroll
            for (int r = 0; r < 4; ++r) {
                float s = 0.f;
                #pragma unroll
                for (int nt = 0; nt < 4; ++nt)
                    s = fmaf(fmaxf(acc2[mt][nt][r], 0.f), w3v[nt], s);
                s += __shfl_xor(s, 1, 64);
                s += __shfl_xor(s, 2, 64);
                s += __shfl_xor(s, 4, 64);
                s += __shfl_xor(s, 8, 64);
                tt[mt][r] = s;   // logit[mt*16 + q*4 + r], replicated in quad
            }
        const int j = n16 & 7;
        float v0 = (j & 2) ? ((j & 1) ? tt[0][3] : tt[0][2]) : ((j & 1) ? tt[0][1] : tt[0][0]);
        float v1 = (j & 2) ? ((j & 1) ? tt[1][3] : tt[1][2]) : ((j & 1) ? tt[1][1] : tt[1][0]);
        float vm = (j & 4) ? v1 : v0;
        const int m = lane & 31;
        const int src = ((m & 12) << 2) | (((m >> 4) & 1) << 2) | (m & 3);
        const float lg = __shfl(vm, src, 64);
        // att3_b dropped: softmax shift-invariant.

        // ---- segment softmax over 32 edges ----
        float mx = lg;
        #pragma unroll
        for (int off = 1; off < 32; off <<= 1)
            mx = fmaxf(mx, __shfl_xor(mx, off, 64));
        const float ex = __expf(lg - mx);
        float sm = ex;
        #pragma unroll
        for (int off = 1; off < 32; off <<= 1)
            sm += __shfl_xor(sm, off, 64);
        const float attv = ex / sm;

        // ---- aggregation: out[n][d] = sum_e att[e]*e_u[e][d]; lane=d ----
        // readlane -> SGPR row index: scalar-pipe addressing; rows L1-hot
        float acco = 0.f;
        #pragma unroll 16
        for (int e2 = 0; e2 < 32; ++e2) {
            int   sidx = __builtin_amdgcn_readlane(idxv, e2);
            float a    = __uint_as_float(__builtin_amdgcn_readlane(__float_as_uint(attv), e2));
            float ev   = PRE ? bf2f(u2b[(size_t)sidx * 64 + lane])
                             : u2f[(size_t)sidx * 64 + lane];
            acco = fmaf(a, ev, acco);
        }
        out[(size_t)n * 64 + lane] = acco;
    }
}

extern "C" void kernel_launch(void* const* d_in, const int* in_sizes, int n_in,
                              void* d_out, int out_size, void* d_ws, size_t ws_size,
                              hipStream_t stream) {
    const int*   nodes = (const int*)d_in[0];
    const int*   neigh = (const int*)d_in[1];
    // d_in[2] segment_ids unused: structurally repeat(arange(N_NODES), 32)
    const float* u2e = (const float*)d_in[3];
    const float* g2e = (const float*)d_in[4];
    const float* w1  = (const float*)d_in[5];
    const float* b1  = (const float*)d_in[6];
    const float* w2  = (const float*)d_in[7];
    const float* b2  = (const float*)d_in[8];
    const float* w3  = (const float*)d_in[9];
    // d_in[10] att3_b unused: cancels in segment softmax
    float* out = (float*)d_out;

    if (ws_size >= WS_NEEDED) {   // verified true in r7; guard kept for safety
        unsigned short* ub = (unsigned short*)(((uintptr_t)d_ws + WS_ALIGN - 1) & ~(uintptr_t)(WS_ALIGN - 1));
        hipLaunchKernelGGL(convert_u2e, dim3((U2E_ELEMS / 8 + 255) / 256), dim3(256),
                           0, stream, u2e, ub);
        hipLaunchKernelGGL(gat_fused<1>, dim3(NBLK), dim3(512), 0, stream,
                           nodes, neigh, u2e, ub, g2e, w1, b1, w2, b2, w3, out);
    } else {
        hipLaunchKernelGGL(gat_fused<0>, dim3(NBLK), dim3(512), 0, stream,
                           nodes, neigh, u2e, (const unsigned short*)nullptr,
                           g2e, w1, b1, w2, b2, w3, out);
    }
}

// Round 10
// 177.140 us; speedup vs baseline: 1.1546x; 1.1546x over previous
//
#include <hip/hip_runtime.h>
#include <hip/hip_bf16.h>

typedef __attribute__((ext_vector_type(8))) short short8;
typedef __attribute__((ext_vector_type(4))) float floatx4;

#define NNODES 40000
#define NPW 4                    // nodes per wave
#define WAVES 8                  // waves per block (512 threads)
#define NPB (NPW * WAVES)        // 32 nodes per block
#define NBLK (NNODES / NPB)      // 1250 blocks, exact

#define U2E_ELEMS (100000 * 64)
#define WS_ALIGN 256
#define WS_NEEDED ((size_t)U2E_ELEMS * 2 + WS_ALIGN)

// Dtype world (MEASURED, r2-r8): float tensors fp32, indices int32, output fp32.
// ~85-90us fixed harness overhead outside kernels (r6-r9 decomposition).
// r7 = 94us kernel is the measured optimum config; r9's bias-fold regressed it
// to 112.5us via scratch spills (WRITE 25->63MB). This round: exact r7 hot loop
// (zero acc init + epilogue bias adds), r9's scaffolding kept.

__device__ __forceinline__ float bf2f(unsigned short s) {
    return __uint_as_float(((unsigned int)s) << 16);
}
__device__ __forceinline__ unsigned short f2bf(float f) {
    unsigned int u = __float_as_uint(f);
    u += 0x7fffu + ((u >> 16) & 1u);   // RNE
    return (unsigned short)(u >> 16);
}
__device__ __forceinline__ unsigned short f2bf_fast(float f) {
#if __has_builtin(__builtin_amdgcn_cvt_pk_bf16_f32)
    auto r = __builtin_amdgcn_cvt_pk_bf16_f32(f, f);   // 1 inst, RNE
    unsigned int u; __builtin_memcpy(&u, &r, 4);
    return (unsigned short)u;
#else
    return f2bf(f);
#endif
}
// 8 consecutive fp32 -> bf16x8 fragment
__device__ __forceinline__ short8 cvt8(const float* fp) {
    floatx4 a = *(const floatx4*)fp;
    floatx4 b = *(const floatx4*)(fp + 4);
    short8 r;
    #pragma unroll
    for (int j = 0; j < 4; ++j) {
        r[j]     = (short)f2bf_fast(a[j]);
        r[4 + j] = (short)f2bf_fast(b[j]);
    }
    return r;
}

// One-shot u2e fp32->bf16 into workspace (~7us: 25.6MB rd / 12.8MB wr)
__global__ __launch_bounds__(256) void convert_u2e(
    const float* __restrict__ u2e, unsigned short* __restrict__ ub) {
    const size_t i = ((size_t)blockIdx.x * 256 + threadIdx.x) * 8;
    if (i < U2E_ELEMS) *(short8*)(ub + i) = cvt8(u2e + i);
}

// One wave = one node (32 edges = 2 MFMA M-tiles). MFMA layouts (m89/m97-verified):
// A-frag: lane holds A[m=lane&15][k=(lane>>4)*8+j]; B-frag: B[k=(lane>>4)*8+j][n=lane&15];
// C/D: col=lane&15, row=(lane>>4)*4+reg.
// NOTE: acc init MUST be zero4 with bias added in the epilogue — initializing
// accumulators from broadcast VGPRs caused scratch spills (r9: +38MB WRITE, +18us).
template<int PRE>
__global__ __launch_bounds__(512, 4) void gat_fused(
    const int*   __restrict__ nodes,
    const int*   __restrict__ neigh,
    const float* __restrict__ u2f,           // [100000][64] fp32 (original)
    const unsigned short* __restrict__ u2b,  // [100000][64] bf16 (ws, PRE=1)
    const float* __restrict__ g2e,           // [50000][64]  fp32
    const float* __restrict__ w1,            // [64][128]
    const float* __restrict__ b1,            // [64]
    const float* __restrict__ w2,            // [64][64]
    const float* __restrict__ b2,            // [64]
    const float* __restrict__ w3,            // [64]
    float* __restrict__ out)                 // [40000][64] fp32
{
    __shared__ alignas(16) short w1f[16 * 64 * 8];      // 16 KB: W1 B-frags (nt,kc)
    __shared__ alignas(16) short w2f[8 * 64 * 8];       // 8 KB:  W2 B-frags
    __shared__ alignas(16) short hbuf[WAVES][32 * 72];  // 36 KB: H1 C->A relayout

    const int tid  = threadIdx.x;
    const int wv   = tid >> 6;
    const int lane = tid & 63;
    const int q    = lane >> 4;
    const int n16  = lane & 15;

    // ---- stage W fragments into LDS (once per block) ----
    for (int i = tid; i < 16 * 64; i += 512) {
        int s = i >> 6, slot = i & 63;
        int nt = s >> 2, kc = s & 3;
        int row = nt * 16 + (slot & 15);
        int k   = kc * 32 + (slot >> 4) * 8;
        *(short8*)&w1f[i * 8] = cvt8(w1 + (size_t)row * 128 + k);
    }
    for (int i = tid; i < 8 * 64; i += 512) {
        int s = i >> 6, slot = i & 63;
        int nt = s >> 1, kc = s & 1;
        int row = nt * 16 + (slot & 15);
        int k   = kc * 32 + (slot >> 4) * 8;
        *(short8*)&w2f[i * 8] = cvt8(w2 + (size_t)row * 64 + k);
    }
    float b1v[4], b2v[4], w3v[4];
    #pragma unroll
    for (int nt = 0; nt < 4; ++nt) {
        b1v[nt] = b1[nt * 16 + n16];
        b2v[nt] = b2[nt * 16 + n16];
        w3v[nt] = w3[nt * 16 + n16];
    }
    __syncthreads();   // weights read-only afterwards; hbuf per-wave exclusive

    const int n0 = blockIdx.x * NPB + wv * NPW;

    // ---- software pipeline state ----
    int gc, vc, c0, c1;    // idx stage feeding current frags
    int gn, vn, d0, d1;    // idx stage one node ahead
    short8 A00, A01, A10, A11, G0, G1;

    auto loadA = [&](int idx, int half) -> short8 {
        if (PRE) return *(const short8*)(u2b + (size_t)idx * 64 + half * 32 + q * 8);
        else     return cvt8(u2f + (size_t)idx * 64 + half * 32 + q * 8);
    };

    {   // prologue: idx(n0) -> frags(n0), idx(n0+1)
        gc = nodes[n0];
        size_t eb = (size_t)n0 * 32;
        vc = neigh[eb + (lane & 31)];
        c0 = neigh[eb + n16];
        c1 = neigh[eb + 16 + n16];
        A00 = loadA(c0, 0); A01 = loadA(c0, 1);
        A10 = loadA(c1, 0); A11 = loadA(c1, 1);
        G0  = cvt8(g2e + (size_t)gc * 64 + q * 8);
        G1  = cvt8(g2e + (size_t)gc * 64 + 32 + q * 8);
        int n1 = n0 + 1;
        gn = nodes[n1];
        size_t eb1 = (size_t)n1 * 32;
        vn = neigh[eb1 + (lane & 31)];
        d0 = neigh[eb1 + n16];
        d1 = neigh[eb1 + 16 + n16];
    }

    const floatx4 zero4 = {0.f, 0.f, 0.f, 0.f};

    for (int it = 0; it < NPW; ++it) {
        const int n = n0 + it;
        const short8 a00 = A00, a01 = A01, a10 = A10, a11 = A11, g0 = G0, g1 = G1;
        const int idxv = vc;

        // ---- layer 1: H1[32x64] = [eu | g] @ W1^T ----
        floatx4 acc[2][4];
        #pragma unroll
        for (int mt = 0; mt < 2; ++mt)
            #pragma unroll
            for (int nt = 0; nt < 4; ++nt) acc[mt][nt] = zero4;
        #pragma unroll
        for (int kc = 0; kc < 4; ++kc) {
            short8 x0 = (kc == 0) ? a00 : (kc == 1) ? a01 : (kc == 2) ? g0 : g1;
            short8 x1 = (kc == 0) ? a10 : (kc == 1) ? a11 : (kc == 2) ? g0 : g1;
            #pragma unroll
            for (int nt = 0; nt < 4; ++nt) {
                short8 b = *(const short8*)&w1f[((nt * 4 + kc) * 64 + lane) * 8];
                acc[0][nt] = __builtin_amdgcn_mfma_f32_16x16x32_bf16(x0, b, acc[0][nt], 0, 0, 0);
                acc[1][nt] = __builtin_amdgcn_mfma_f32_16x16x32_bf16(x1, b, acc[1][nt], 0, 0, 0);
            }
        }

        // ---- prefetch node it+1 frags, node it+2 indices ----
        if (it < NPW - 1) {
            A00 = loadA(d0, 0); A01 = loadA(d0, 1);
            A10 = loadA(d1, 0); A11 = loadA(d1, 1);
            G0  = cvt8(g2e + (size_t)gn * 64 + q * 8);
            G1  = cvt8(g2e + (size_t)gn * 64 + 32 + q * 8);
            gc = gn; vc = vn; c0 = d0; c1 = d1;
            int nn = n0 + it + 2; if (nn > NNODES - 1) nn = NNODES - 1;
            gn = nodes[nn];
            size_t eb2 = (size_t)nn * 32;
            vn = neigh[eb2 + (lane & 31)];
            d0 = neigh[eb2 + n16];
            d1 = neigh[eb2 + 16 + n16];
        }

        // ---- epilogue 1: +b1, relu, bf16 pack, C-layout -> row-major LDS ----
        __builtin_amdgcn_wave_barrier();   // prior a2 reads precede overwrite
        #pragma unroll
        for (int mt = 0; mt < 2; ++mt)
            #pragma unroll
            for (int nt = 0; nt < 4; ++nt)
                #pragma unroll
                for (int r = 0; r < 4; ++r) {
                    float v = fmaxf(acc[mt][nt][r] + b1v[nt], 0.f);
                    hbuf[wv][(mt * 16 + q * 4 + r) * 72 + nt * 16 + n16] = (short)f2bf_fast(v);
                }
        __builtin_amdgcn_wave_barrier();

        // ---- layer 2 A-frags from LDS (intra-wave, in-order) ----
        short8 a2[2][2];
        #pragma unroll
        for (int mt = 0; mt < 2; ++mt)
            #pragma unroll
            for (int kc = 0; kc < 2; ++kc)
                a2[mt][kc] = *(const short8*)&hbuf[wv][(mt * 16 + n16) * 72 + kc * 32 + q * 8];

        floatx4 acc2[2][4];
        #pragma unroll
        for (int mt = 0; mt < 2; ++mt)
            #pragma unroll
            for (int nt = 0; nt < 4; ++nt) acc2[mt][nt] = zero4;
        #pragma unroll
        for (int kc = 0; kc < 2; ++kc)
            #pragma unroll
            for (int nt = 0; nt < 4; ++nt) {
                short8 b = *(const short8*)&w2f[((nt * 2 + kc) * 64 + lane) * 8];
                acc2[0][nt] = __builtin_amdgcn_mfma_f32_16x16x32_bf16(a2[0][kc], b, acc2[0][nt], 0, 0, 0);
                acc2[1][nt] = __builtin_amdgcn_mfma_f32_16x16x32_bf16(a2[1][kc], b, acc2[1][nt], 0, 0, 0);
            }

        // ---- logits in registers: tt[mt][r] = sum_nt relu(acc2+b2)*w3 ----
        float tt[2][4];
        #pragma unroll
        for (int mt = 0; mt < 2; ++mt)
            #pragma unroll
            for (int r = 0; r < 4; ++r) {
                float s = 0.f;
                #pragma unroll
                for (int nt = 0; nt < 4; ++nt)
                    s = fmaf(fmaxf(acc2[mt][nt][r] + b2v[nt], 0.f), w3v[nt], s);
                s += __shfl_xor(s, 1, 64);
                s += __shfl_xor(s, 2, 64);
                s += __shfl_xor(s, 4, 64);
                s += __shfl_xor(s, 8, 64);
                tt[mt][r] = s;   // logit[mt*16 + q*4 + r], replicated in quad
            }
        const int j = n16 & 7;
        float v0 = (j & 2) ? ((j & 1) ? tt[0][3] : tt[0][2]) : ((j & 1) ? tt[0][1] : tt[0][0]);
        float v1 = (j & 2) ? ((j & 1) ? tt[1][3] : tt[1][2]) : ((j & 1) ? tt[1][1] : tt[1][0]);
        float vm = (j & 4) ? v1 : v0;
        const int m = lane & 31;
        const int src = ((m & 12) << 2) | (((m >> 4) & 1) << 2) | (m & 3);
        const float lg = __shfl(vm, src, 64);
        // att3_b dropped: softmax shift-invariant.

        // ---- segment softmax over 32 edges ----
        float mx = lg;
        #pragma unroll
        for (int off = 1; off < 32; off <<= 1)
            mx = fmaxf(mx, __shfl_xor(mx, off, 64));
        const float ex = __expf(lg - mx);
        float sm = ex;
        #pragma unroll
        for (int off = 1; off < 32; off <<= 1)
            sm += __shfl_xor(sm, off, 64);
        const float attv = ex / sm;

        // ---- aggregation: out[n][d] = sum_e att[e]*e_u[e][d]; lane=d ----
        float acco = 0.f;
        #pragma unroll 16
        for (int e2 = 0; e2 < 32; ++e2) {
            int   sidx = __builtin_amdgcn_readlane(idxv, e2);
            float a    = __uint_as_float(__builtin_amdgcn_readlane(__float_as_uint(attv), e2));
            float ev   = PRE ? bf2f(u2b[(size_t)sidx * 64 + lane])
                             : u2f[(size_t)sidx * 64 + lane];
            acco = fmaf(a, ev, acco);
        }
        out[(size_t)n * 64 + lane] = acco;
    }
}

extern "C" void kernel_launch(void* const* d_in, const int* in_sizes, int n_in,
                              void* d_out, int out_size, void* d_ws, size_t ws_size,
                              hipStream_t stream) {
    const int*   nodes = (const int*)d_in[0];
    const int*   neigh = (const int*)d_in[1];
    // d_in[2] segment_ids unused: structurally repeat(arange(N_NODES), 32)
    const float* u2e = (const float*)d_in[3];
    const float* g2e = (const float*)d_in[4];
    const float* w1  = (const float*)d_in[5];
    const float* b1  = (const float*)d_in[6];
    const float* w2  = (const float*)d_in[7];
    const float* b2  = (const float*)d_in[8];
    const float* w3  = (const float*)d_in[9];
    // d_in[10] att3_b unused: cancels in segment softmax
    float* out = (float*)d_out;

    if (ws_size >= WS_NEEDED) {   // true in practice (r7); guard for safety
        unsigned short* ub = (unsigned short*)(((uintptr_t)d_ws + WS_ALIGN - 1) & ~(uintptr_t)(WS_ALIGN - 1));
        hipLaunchKernelGGL(convert_u2e, dim3((U2E_ELEMS / 8 + 255) / 256), dim3(256),
                           0, stream, u2e, ub);
        hipLaunchKernelGGL(gat_fused<1>, dim3(NBLK), dim3(512), 0, stream,
                           nodes, neigh, u2e, ub, g2e, w1, b1, w2, b2, w3, out);
    } else {
        hipLaunchKernelGGL(gat_fused<0>, dim3(NBLK), dim3(512), 0, stream,
                           nodes, neigh, u2e, (const unsigned short*)nullptr,
                           g2e, w1, b1, w2, b2, w3, out);
    }
}